// Round 3
// baseline (15245.064 us; speedup 1.0000x reference)
//
#include <hip/hip_runtime.h>
#include <hip/hip_cooperative_groups.h>

namespace cg = cooperative_groups;

typedef unsigned short ushort_t;
typedef float  f32x4  __attribute__((ext_vector_type(4)));
typedef __bf16 bf16x8 __attribute__((ext_vector_type(8)));

// Problem sizes (fixed): B=64, S=512, D=1024, H=1024, 4H=4096
#define NB   64
#define NS   512
#define ND   1024
#define NH   1024
#define NG   4096   // 4*H
#define HPAD 1032   // 1024 + 8: keeps ds_read_b128 16B-aligned, breaks bank stride

// ---------- helpers ----------
__device__ __forceinline__ ushort_t f2bf(float f) {
  unsigned u = __float_as_uint(f);
  u += 0x7FFFu + ((u >> 16) & 1u);   // round-to-nearest-even
  return (ushort_t)(u >> 16);
}
__device__ __forceinline__ float bf2f(ushort_t u) {
  return __uint_as_float(((unsigned)u) << 16);
}
__device__ __forceinline__ float sigmoid_f(float x) {
  return 1.0f / (1.0f + __expf(-x));
}
__device__ __forceinline__ float tanh_f(float x) {
  return 1.0f - 2.0f / (__expf(2.0f * x) + 1.0f);
}

// ---------- prep: fp32 -> bf16 conversions ----------
__global__ __launch_bounds__(256) void cvt_x_kernel(const float4* __restrict__ x,
                                                    ushort_t* __restrict__ xb) {
  int i = blockIdx.x * 256 + threadIdx.x;
  float4 v = x[i];
  ushort4 o;
  o.x = f2bf(v.x); o.y = f2bf(v.y); o.z = f2bf(v.z); o.w = f2bf(v.w);
  *(ushort4*)(xb + (size_t)i * 4) = o;
}

__global__ __launch_bounds__(256) void cvt_w_kernel(const float4* __restrict__ W,
                                                    ushort_t* __restrict__ Wx,
                                                    ushort_t* __restrict__ Wh) {
  int i = blockIdx.x * 256 + threadIdx.x;
  float4 v = W[i];
  int e = i * 4;
  int n = e >> 11;        // row of W  (2048 cols)
  int c = e & 2047;       // col of W
  ushort4 o;
  o.x = f2bf(v.x); o.y = f2bf(v.y); o.z = f2bf(v.z); o.w = f2bf(v.w);
  ushort_t* dst = (c < ND) ? (Wx + (size_t)n * ND + c)
                           : (Wh + (size_t)n * NH + (c - ND));
  *(ushort4*)dst = o;
}

// ---------- pre-GEMM: PG[t][b][n] = x @ Wx^T + bias  (bf16 out) ----------
__global__ __launch_bounds__(256) void pregemm_kernel(
    const ushort_t* __restrict__ xb, const ushort_t* __restrict__ Wx,
    const float* __restrict__ bias, ushort_t* __restrict__ PG) {
  int bid  = blockIdx.x;
  int mblk = bid >> 5;        // 256 m-blocks
  int nblk = bid & 31;        // 32 n-blocks
  int tid  = threadIdx.x;
  int lane = tid & 63, w = tid >> 6;
  int l15  = lane & 15, q = lane >> 4;
  int row0 = mblk * 128 + (w >> 1) * 64;
  int col0 = nblk * 128 + (w & 1) * 64;
  const ushort_t* aBase = xb + (size_t)(row0 + l15) * ND + q * 8;
  const ushort_t* bBase = Wx + (size_t)(col0 + l15) * ND + q * 8;

  f32x4 acc[4][4] = {};
#pragma unroll 2
  for (int k0 = 0; k0 < ND; k0 += 32) {
    bf16x8 a[4], b[4];
#pragma unroll
    for (int mi = 0; mi < 4; ++mi)
      a[mi] = *reinterpret_cast<const bf16x8*>(aBase + (size_t)mi * 16 * ND + k0);
#pragma unroll
    for (int ni = 0; ni < 4; ++ni)
      b[ni] = *reinterpret_cast<const bf16x8*>(bBase + (size_t)ni * 16 * ND + k0);
#pragma unroll
    for (int mi = 0; mi < 4; ++mi)
#pragma unroll
      for (int ni = 0; ni < 4; ++ni)
        acc[mi][ni] = __builtin_amdgcn_mfma_f32_16x16x32_bf16(a[mi], b[ni], acc[mi][ni], 0, 0, 0);
  }
#pragma unroll
  for (int ni = 0; ni < 4; ++ni) {
    int n = col0 + ni * 16 + l15;
    float bv = bias[n];
#pragma unroll
    for (int mi = 0; mi < 4; ++mi) {
#pragma unroll
      for (int r = 0; r < 4; ++r) {
        int m  = row0 + mi * 16 + q * 4 + r;
        int bb = m >> 9;          // batch
        int t  = m & 511;         // time
        PG[((size_t)t * NB + bb) * NG + n] = f2bf(acc[mi][ni][r] + bv);
      }
    }
  }
}

// ---------- recurrent: persistent cooperative kernel ----------
// 64 blocks x 1024 thr (16 waves). Block owns j in [bid*16, bid*16+16).
// Custom monotone-counter barrier replaces cg::grid.sync() (ROCm grid.sync
// measured ~22 us/step overhead here: R1 and R2 both pinned at ~27 us/step
// with completely different compute structure).
__global__ __launch_bounds__(1024) void lstm_rec_kernel(
    const ushort_t* __restrict__ PG, const ushort_t* __restrict__ Wh,
    ushort_t* hbuf, float* __restrict__ out, unsigned* __restrict__ bar) {
  __shared__ ushort_t lds_h[64 * HPAD];     // 132096 B
  __shared__ float lds_g[4][64][17];        // 17408 B  (total 149504 <= 163840)

  int bid = blockIdx.x;                // 0..63
  int j0  = bid * 16;
  int tid = threadIdx.x;
  int lane = tid & 63, w = tid >> 6;
  int g = w & 3, ms = w >> 2;
  int l15  = lane & 15, q = lane >> 4;
  int jj   = tid & 15, m = tid >> 4;   // cell phase: exactly 1 element/thread

  const ushort_t* bB   = Wh + (size_t)(g * NH + j0 + l15) * NH + q * 8;
  const ushort_t* aRow = lds_h + (size_t)(ms * 16 + l15) * HPAD + q * 8;
  float c_reg = 0.f;                   // c lives in a register for all 512 steps

  // PG prefetch for t=0 (PG is constant during this kernel -> safe to hoist
  // across barriers/fences)
  const ushort_t* pp = PG + (size_t)m * NG + j0 + jj;
  ushort_t pg0 = pp[0], pg1 = pp[NH], pg2 = pp[2 * NH], pg3 = pp[3 * NH];

  for (int t = 0; t < NS; ++t) {
    const ushort_t* hb = hbuf + (size_t)(t & 1) * (NB * NH);
    ushort_t*       hn = hbuf + (size_t)((t & 1) ^ 1) * (NB * NH);

    // stage h into LDS: 8 x 16B per thread, fully coalesced, all independent
#pragma unroll
    for (int it = 0; it < 8; ++it) {
      int e   = it * 8192 + tid * 8;   // element index, 16B chunks
      int row = e >> 10;
      int col = e & 1023;
      uint4 v = *(const uint4*)(hb + e);
      *(uint4*)(lds_h + row * HPAD + col) = v;
    }
    __syncthreads();

    // GEMM: 16x16 tile, K=1024 split into 2 interleaved acc chains
    f32x4 acc0 = {}, acc1 = {};
#pragma unroll 4
    for (int k0 = 0; k0 < NH / 2; k0 += 32) {
      bf16x8 a0 = *reinterpret_cast<const bf16x8*>(aRow + k0);
      bf16x8 b0 = *reinterpret_cast<const bf16x8*>(bB + k0);
      bf16x8 a1 = *reinterpret_cast<const bf16x8*>(aRow + 512 + k0);
      bf16x8 b1 = *reinterpret_cast<const bf16x8*>(bB + 512 + k0);
      acc0 = __builtin_amdgcn_mfma_f32_16x16x32_bf16(a0, b0, acc0, 0, 0, 0);
      acc1 = __builtin_amdgcn_mfma_f32_16x16x32_bf16(a1, b1, acc1, 0, 0, 0);
    }
    // C/D layout: col = lane&15, row = q*4 + r
#pragma unroll
    for (int r = 0; r < 4; ++r)
      lds_g[g][ms * 16 + q * 4 + r][l15] = acc0[r] + acc1[r];

    // prefetch PG for t+1 while lds_g settles
    ushort_t npg0 = 0, npg1 = 0, npg2 = 0, npg3 = 0;
    if (t + 1 < NS) {
      const ushort_t* np = PG + ((size_t)(t + 1) * NB + m) * NG + j0 + jj;
      npg0 = np[0]; npg1 = np[NH]; npg2 = np[2 * NH]; npg3 = np[3 * NH];
    }
    __syncthreads();

    // cell: 1 (m, jj) element per thread
    float gi = lds_g[0][m][jj] + bf2f(pg0);
    float gf = lds_g[1][m][jj] + bf2f(pg1);
    float go = lds_g[2][m][jj] + bf2f(pg2);
    float gg = lds_g[3][m][jj] + bf2f(pg3);
    float cn = sigmoid_f(gf) * c_reg + sigmoid_f(gi) * tanh_f(gg);
    float hv = sigmoid_f(go) * tanh_f(cn);
    c_reg = cn;
    out[((size_t)m * NS + t) * NH + j0 + jj] = hv;
    hn[(size_t)m * NH + j0 + jj] = f2bf(hv);
    if (t == NS - 1) {
      out[(size_t)NB * NS * NH + (size_t)m * NH + j0 + jj] = hv;                      // final h
      out[(size_t)NB * NS * NH + (size_t)NB * NH + (size_t)m * NH + j0 + jj] = cn;    // final c
    }
    pg0 = npg0; pg1 = npg1; pg2 = npg2; pg3 = npg3;

    // ---- fast device barrier ----
    // __syncthreads drains this block's h stores to L2 (vmcnt(0) before
    // s_barrier); the release-add publishes them agent-wide.
    __syncthreads();
    if (tid == 0) {
      __hip_atomic_fetch_add(bar, 1u, __ATOMIC_RELEASE, __HIP_MEMORY_SCOPE_AGENT);
      unsigned target = 64u * (unsigned)(t + 1);
      while (__hip_atomic_load(bar, __ATOMIC_ACQUIRE, __HIP_MEMORY_SCOPE_AGENT) < target) {}
    }
    __syncthreads();
    // per-wave acquire: invalidate stale L1/L2 lines before re-reading h
    __builtin_amdgcn_fence(__ATOMIC_ACQUIRE, "agent");
  }
}

// ---------- launch ----------
extern "C" void kernel_launch(void* const* d_in, const int* in_sizes, int n_in,
                              void* d_out, int out_size, void* d_ws, size_t ws_size,
                              hipStream_t stream) {
  const float* x    = (const float*)d_in[0];
  const float* W    = (const float*)d_in[1];
  const float* bias = (const float*)d_in[2];
  float* out = (float*)d_out;

  const size_t off_bar  = 0;                       // 256 B (one counter used)
  const size_t off_hbuf = 256;                     // 2 * 64*1024 bf16 = 262144
  const size_t off_Wx   = off_hbuf + 262144;       // 8388608
  const size_t off_Wh   = off_Wx + 8388608;        // 8388608
  const size_t off_xb   = off_Wh + 8388608;        // 67108864
  const size_t off_PG   = off_xb + 67108864;       // 268435456
  const size_t need     = off_PG + 268435456;      // ~336.3 MB
  if (ws_size < need) return;

  char* ws = (char*)d_ws;
  unsigned*  bar  = (unsigned*)(ws + off_bar);
  ushort_t* hbuf = (ushort_t*)(ws + off_hbuf);
  ushort_t* Wx   = (ushort_t*)(ws + off_Wx);
  ushort_t* Wh   = (ushort_t*)(ws + off_Wh);
  ushort_t* xb   = (ushort_t*)(ws + off_xb);
  ushort_t* PG   = (ushort_t*)(ws + off_PG);

  // zero barrier counter + h0 (both ping-pong buffers) every launch
  hipMemsetAsync(ws, 0, off_hbuf + 262144, stream);

  cvt_x_kernel<<<32768, 256, 0, stream>>>((const float4*)x, xb);
  cvt_w_kernel<<<8192, 256, 0, stream>>>((const float4*)W, Wx, Wh);
  pregemm_kernel<<<8192, 256, 0, stream>>>(xb, Wx, bias, PG);

  void* args[] = { (void*)&PG, (void*)&Wh, (void*)&hbuf, (void*)&out, (void*)&bar };
  hipLaunchCooperativeKernel((void*)lstm_rec_kernel, dim3(64), dim3(1024),
                             args, 0, stream);
}